// Round 1
// baseline (43.479 us; speedup 1.0000x reference)
//
#include <hip/hip_runtime.h>
#include <stdint.h>

#define RANKS 8
#define MDIM 8192   // B*T*D / 1024 rows
#define KDIM 1024
#define NDIM 1024
#define BM 128
#define BN 128
#define BK 64

typedef __bf16 bf16x8 __attribute__((ext_vector_type(8)));
typedef unsigned short u16x8 __attribute__((ext_vector_type(8)));
typedef float f32x4 __attribute__((ext_vector_type(4)));

__device__ __forceinline__ unsigned short f2bf(float f) {
  union { float f; uint32_t u; } v; v.f = f;
  uint32_t u = v.u;
  u += 0x7FFFu + ((u >> 16) & 1u);   // round-to-nearest-even
  return (unsigned short)(u >> 16);
}

// Hamilton block tables: H[r, kb*4+ks, sb*4+ss] = sign[kb][sb] * A[r, comp[kb][sb], ks, ss]
//   H = [[ r,-i,-j,-k],
//        [ i, r,-k, j],
//        [ j, k, r,-i],
//        [ k,-j, i, r]]
__constant__ int   c_comp[4][4] = {{0,1,2,3},{1,0,3,2},{2,3,0,1},{3,2,1,0}};
__constant__ float c_sign[4][4] = {{1.f,-1.f,-1.f,-1.f},
                                   {1.f, 1.f,-1.f, 1.f},
                                   {1.f, 1.f, 1.f,-1.f},
                                   {1.f,-1.f, 1.f, 1.f}};

// ---------------------------------------------------------------------------
// W[p][q] = sum_r H[r,k,s] * fB[r,j,i],  p = k*64+j, q = s*64+i.  bf16 out.
// grid 1024 x 256 threads; each thread does 4 consecutive q for one p.
// ---------------------------------------------------------------------------
__global__ void build_W(const float* __restrict__ A, const float* __restrict__ fB,
                        unsigned short* __restrict__ W) {
  int idx = blockIdx.x * 256 + threadIdx.x;
  int p  = idx >> 8;          // 0..1023
  int q4 = (idx & 255) << 2;  // 0..1020, 4 consecutive q share s
  int k = p >> 6, j = p & 63;
  int kb = k >> 2, ks = k & 3;
  int s = q4 >> 6;
  int sb = s >> 2, ss = s & 3;
  int   comp = c_comp[kb][sb];
  float sgn  = c_sign[kb][sb];
  float o0 = 0.f, o1 = 0.f, o2 = 0.f, o3 = 0.f;
  int i0 = q4 & 63;
#pragma unroll
  for (int r = 0; r < RANKS; ++r) {
    float h = sgn * A[r * 64 + comp * 16 + ks * 4 + ss];
    const float* fb = fB + r * 4096 + j * 64 + i0;
    o0 += h * fb[0]; o1 += h * fb[1]; o2 += h * fb[2]; o3 += h * fb[3];
  }
  ushort4 st;
  st.x = f2bf(o0); st.y = f2bf(o1); st.z = f2bf(o2); st.w = f2bf(o3);
  *reinterpret_cast<ushort4*>(W + (size_t)p * KDIM + q4) = st;
}

// ---------------------------------------------------------------------------
// x (f32) -> bf16 bits, 8 elems/thread, fully coalesced.
// ---------------------------------------------------------------------------
__global__ void cvt_x(const float* __restrict__ x, unsigned short* __restrict__ xb) {
  size_t base = ((size_t)blockIdx.x * 256 + threadIdx.x) * 8;
  float4 a = *reinterpret_cast<const float4*>(x + base);
  float4 b = *reinterpret_cast<const float4*>(x + base + 4);
  u16x8 v;
  v[0] = f2bf(a.x); v[1] = f2bf(a.y); v[2] = f2bf(a.z); v[3] = f2bf(a.w);
  v[4] = f2bf(b.x); v[5] = f2bf(b.y); v[6] = f2bf(b.z); v[7] = f2bf(b.w);
  *reinterpret_cast<u16x8*>(xb + base) = v;
}

// ---------------------------------------------------------------------------
// GEMM: out[m][n] = sum_k Xb[m][k] * W[n][k] + bias[n]
// m97-style: 128x128 tile, BK=64, 4 waves (2x2), 4x4 16x16x32 frags/wave,
// double-buffered LDS, global_load_lds width 16.
// ---------------------------------------------------------------------------
__device__ __forceinline__ void gload16(const unsigned short* g, unsigned short* l) {
  __builtin_amdgcn_global_load_lds(
      (const __attribute__((address_space(1))) unsigned int*)(uintptr_t)g,
      (__attribute__((address_space(3))) unsigned int*)(uintptr_t)l,
      16, 0, 0);
}

__global__ __launch_bounds__(256, 2) void gemm_ham(
    const unsigned short* __restrict__ Xb, const unsigned short* __restrict__ W,
    const float* __restrict__ bias, float* __restrict__ out) {
  __shared__ unsigned short Asm_[2][BM * BK];
  __shared__ unsigned short Bsm_[2][BN * BK];
  const int tid  = threadIdx.x;
  const int lane = tid & 63;
  const int wid  = tid >> 6;
  const int wr = wid >> 1, wc = wid & 1;
  const int row0 = blockIdx.x * BM;
  const int col0 = blockIdx.y * BN;

  f32x4 acc[4][4];
  f32x4 zero = {0.f, 0.f, 0.f, 0.f};
#pragma unroll
  for (int m = 0; m < 4; ++m)
#pragma unroll
    for (int n = 0; n < 4; ++n) acc[m][n] = zero;

  auto stage = [&](int b, int k0) {
#pragma unroll
    for (int c = 0; c < 4; ++c) {
      int eo = c * 2048 + tid * 8;      // element offset in [128][64] tile
      int rr = eo >> 6, cc = eo & 63;
      gload16(Xb + (size_t)(row0 + rr) * KDIM + k0 + cc, &Asm_[b][eo]);
      gload16(W  + (size_t)(col0 + rr) * KDIM + k0 + cc, &Bsm_[b][eo]);
    }
  };

  stage(0, 0);
  __syncthreads();
  int cur = 0;
  const int rb   = lane & 15;
  const int krd0 = (lane >> 4) * 8;
#pragma unroll 1
  for (int kt = 0; kt < KDIM / BK; ++kt) {
    if (kt + 1 < KDIM / BK) stage(cur ^ 1, (kt + 1) * BK);
#pragma unroll
    for (int kk = 0; kk < 2; ++kk) {
      const int krd = kk * 32 + krd0;
      bf16x8 af[4], bfr[4];
#pragma unroll
      for (int m = 0; m < 4; ++m)
        af[m] = __builtin_bit_cast(bf16x8,
            *reinterpret_cast<const u16x8*>(&Asm_[cur][(wr * 64 + m * 16 + rb) * BK + krd]));
#pragma unroll
      for (int n = 0; n < 4; ++n)
        bfr[n] = __builtin_bit_cast(bf16x8,
            *reinterpret_cast<const u16x8*>(&Bsm_[cur][(wc * 64 + n * 16 + rb) * BK + krd]));
#pragma unroll
      for (int m = 0; m < 4; ++m)
#pragma unroll
        for (int n = 0; n < 4; ++n)
          acc[m][n] = __builtin_amdgcn_mfma_f32_16x16x32_bf16(af[m], bfr[n], acc[m][n], 0, 0, 0);
    }
    __syncthreads();
    cur ^= 1;
  }

  // C/D layout (verified m89): col = lane&15, row = (lane>>4)*4 + reg
  const int crow = row0 + wr * 64 + (lane >> 4) * 4;
  const int ccol = col0 + wc * 64 + (lane & 15);
#pragma unroll
  for (int n = 0; n < 4; ++n) {
    int c = ccol + n * 16;
    float bv = bias[c];
#pragma unroll
    for (int m = 0; m < 4; ++m)
#pragma unroll
      for (int v = 0; v < 4; ++v)
        out[(size_t)(crow + m * 16 + v) * NDIM + c] = acc[m][n][v] + bv;
  }
}

// ---------------------------------------------------------------------------
// Workspace-free fallback (slow but correct): one block per row n.
// ---------------------------------------------------------------------------
__global__ void fallback_kernel(const float* __restrict__ x, const float* __restrict__ A,
                                const float* __restrict__ fB, const float* __restrict__ bias,
                                float* __restrict__ out) {
  __shared__ float xrow[1024];
  const int n = blockIdx.x;
  const int tid = threadIdx.x;
  for (int t = tid; t < 1024; t += 256) xrow[t] = x[(size_t)n * 1024 + t];
  __syncthreads();
  for (int pp = 0; pp < 4; ++pp) {
    int p = pp * 256 + tid;
    int k = p >> 6, j = p & 63;
    int kb = k >> 2, ks = k & 3;
    float accv = 0.f;
    for (int s = 0; s < 16; ++s) {
      int sb = s >> 2, ss = s & 3;
      int comp = c_comp[kb][sb];
      float sgn = c_sign[kb][sb];
      float hA[RANKS];
#pragma unroll
      for (int r = 0; r < RANKS; ++r) hA[r] = sgn * A[r * 64 + comp * 16 + ks * 4 + ss];
      for (int i = 0; i < 64; ++i) {
        float w = 0.f;
#pragma unroll
        for (int r = 0; r < RANKS; ++r) w += hA[r] * fB[r * 4096 + j * 64 + i];
        accv += xrow[s * 64 + i] * w;
      }
    }
    out[(size_t)n * 1024 + p] = accv + bias[p];
  }
}

extern "C" void kernel_launch(void* const* d_in, const int* in_sizes, int n_in,
                              void* d_out, int out_size, void* d_ws, size_t ws_size,
                              hipStream_t stream) {
  const float* x    = (const float*)d_in[0];
  const float* A    = (const float*)d_in[1];
  const float* fB   = (const float*)d_in[2];
  const float* bias = (const float*)d_in[3];
  float* out = (float*)d_out;

  const size_t needW = (size_t)NDIM * KDIM * sizeof(unsigned short);
  const size_t needX = (size_t)MDIM * KDIM * sizeof(unsigned short);
  if (ws_size >= needW + needX) {
    unsigned short* W  = (unsigned short*)d_ws;
    unsigned short* Xb = W + (size_t)NDIM * KDIM;
    build_W<<<dim3(1024), dim3(256), 0, stream>>>(A, fB, W);
    cvt_x<<<dim3((MDIM * KDIM) / (8 * 256)), dim3(256), 0, stream>>>(x, Xb);
    gemm_ham<<<dim3(MDIM / BM, NDIM / BN), dim3(256), 0, stream>>>(Xb, W, bias, out);
  } else {
    fallback_kernel<<<dim3(MDIM), dim3(256), 0, stream>>>(x, A, fB, bias, out);
  }
}

// Round 2
// 40.542 us; speedup vs baseline: 1.0725x; 1.0725x over previous
//
#include <hip/hip_runtime.h>
#include <stdint.h>

#define RANKS 8
#define MDIM 8192   // B*T*D / 1024 rows
#define KDIM 1024
#define NDIM 1024
#define BM 128
#define BN 128
#define BK 64
#define NT (KDIM / BK)

typedef __bf16 bf16x8 __attribute__((ext_vector_type(8)));
typedef unsigned short u16x8 __attribute__((ext_vector_type(8)));
typedef float f32x4 __attribute__((ext_vector_type(4)));

__device__ __forceinline__ unsigned short f2bf(float f) {
  union { float f; uint32_t u; } v; v.f = f;
  uint32_t u = v.u;
  u += 0x7FFFu + ((u >> 16) & 1u);   // round-to-nearest-even
  return (unsigned short)(u >> 16);
}

// Hamilton block tables: H[r, kb*4+ks, sb*4+ss] = sign[kb][sb] * A[r, comp[kb][sb], ks, ss]
__constant__ int   c_comp[4][4] = {{0,1,2,3},{1,0,3,2},{2,3,0,1},{3,2,1,0}};
__constant__ float c_sign[4][4] = {{1.f,-1.f,-1.f,-1.f},
                                   {1.f, 1.f,-1.f, 1.f},
                                   {1.f, 1.f, 1.f,-1.f},
                                   {1.f,-1.f, 1.f, 1.f}};

// ---------------------------------------------------------------------------
// W[p][q] = sum_r H[r,k,s] * fB[r,j,i],  p = k*64+j, q = s*64+i.  bf16 out.
// ---------------------------------------------------------------------------
__global__ void build_W(const float* __restrict__ A, const float* __restrict__ fB,
                        unsigned short* __restrict__ W) {
  int idx = blockIdx.x * 256 + threadIdx.x;
  int p  = idx >> 8;
  int q4 = (idx & 255) << 2;
  int k = p >> 6, j = p & 63;
  int kb = k >> 2, ks = k & 3;
  int s = q4 >> 6;
  int sb = s >> 2, ss = s & 3;
  int   comp = c_comp[kb][sb];
  float sgn  = c_sign[kb][sb];
  float o0 = 0.f, o1 = 0.f, o2 = 0.f, o3 = 0.f;
  int i0 = q4 & 63;
#pragma unroll
  for (int r = 0; r < RANKS; ++r) {
    float h = sgn * A[r * 64 + comp * 16 + ks * 4 + ss];
    const float* fb = fB + r * 4096 + j * 64 + i0;
    o0 += h * fb[0]; o1 += h * fb[1]; o2 += h * fb[2]; o3 += h * fb[3];
  }
  ushort4 st;
  st.x = f2bf(o0); st.y = f2bf(o1); st.z = f2bf(o2); st.w = f2bf(o3);
  *reinterpret_cast<ushort4*>(W + (size_t)p * KDIM + q4) = st;
}

// ---------------------------------------------------------------------------
// Fused GEMM: out[m][n] = sum_k bf16(x[m][k]) * W[n][k] + bias[n]
// A-side: reg-staged f32 x -> cvt bf16 -> ds_write_b128 (kills the cvt pass).
// B-side: global_load_lds width 16 from prebuilt bf16 W.
// XCD-chunked bijective swizzle: flat = a + 8b + 64c -> bx = 8a+b, by = c,
// so the 8 by-blocks sharing one A-panel are co-resident on one XCD (L2 hit).
// ---------------------------------------------------------------------------
__device__ __forceinline__ void gload16(const unsigned short* g, unsigned short* l) {
  __builtin_amdgcn_global_load_lds(
      (const __attribute__((address_space(1))) unsigned int*)(uintptr_t)g,
      (__attribute__((address_space(3))) unsigned int*)(uintptr_t)l,
      16, 0, 0);
}

__global__ __launch_bounds__(256, 2) void gemm_ham(
    const float* __restrict__ x, const unsigned short* __restrict__ W,
    const float* __restrict__ bias, float* __restrict__ out) {
  __shared__ unsigned short Asm_[2][BM * BK];
  __shared__ unsigned short Bsm_[2][BN * BK];
  const int tid  = threadIdx.x;
  const int lane = tid & 63;
  const int wid  = tid >> 6;
  const int wr = wid >> 1, wc = wid & 1;

  // bijective XCD-chunk swizzle over 512 blocks (8 XCDs x 64)
  const int flat = blockIdx.x;
  const int xa = flat & 7, xb = (flat >> 3) & 7, xc = flat >> 6;
  const int bx = xa * 8 + xb;       // 0..63  (M block)
  const int by = xc;                // 0..7   (N block)
  const int row0 = bx * BM;
  const int col0 = by * BN;

  f32x4 acc[4][4];
  f32x4 zero = {0.f, 0.f, 0.f, 0.f};
#pragma unroll
  for (int m = 0; m < 4; ++m)
#pragma unroll
    for (int n = 0; n < 4; ++n) acc[m][n] = zero;

  float4 ar[4][2];   // reg-staged A tile slice (32 f32/thread)

  auto loadA = [&](int kt) {
    const int k0 = kt * BK;
#pragma unroll
    for (int g = 0; g < 4; ++g) {
      int idx8 = g * 256 + tid;
      int row = idx8 >> 3, col8 = (idx8 & 7) << 3;
      const float* src = x + (size_t)(row0 + row) * KDIM + k0 + col8;
      ar[g][0] = *reinterpret_cast<const float4*>(src);
      ar[g][1] = *reinterpret_cast<const float4*>(src + 4);
    }
  };
  auto writeA = [&](int b) {
#pragma unroll
    for (int g = 0; g < 4; ++g) {
      int idx8 = g * 256 + tid;
      int row = idx8 >> 3, col8 = (idx8 & 7) << 3;
      bf16x8 v;
      v[0] = (__bf16)ar[g][0].x; v[1] = (__bf16)ar[g][0].y;
      v[2] = (__bf16)ar[g][0].z; v[3] = (__bf16)ar[g][0].w;
      v[4] = (__bf16)ar[g][1].x; v[5] = (__bf16)ar[g][1].y;
      v[6] = (__bf16)ar[g][1].z; v[7] = (__bf16)ar[g][1].w;
      *reinterpret_cast<bf16x8*>(&Asm_[b][row * BK + col8]) = v;
    }
  };
  auto stageB = [&](int b, int k0) {
#pragma unroll
    for (int c = 0; c < 4; ++c) {
      int eo = c * 2048 + tid * 8;
      int rr = eo >> 6, cc = eo & 63;
      gload16(W + (size_t)(col0 + rr) * KDIM + k0 + cc, &Bsm_[b][eo]);
    }
  };

  // prologue: tile 0
  loadA(0);
  writeA(0);
  stageB(0, 0);
  __syncthreads();

  int cur = 0;
  const int rb   = lane & 15;
  const int krd0 = (lane >> 4) * 8;
#pragma unroll 1
  for (int kt = 0; kt < NT; ++kt) {
    const bool next = (kt + 1 < NT);
    if (next) {
      loadA(kt + 1);                       // f32 loads in flight under MFMA
      stageB(cur ^ 1, (kt + 1) * BK);      // async global->LDS for W
    }
#pragma unroll
    for (int kk = 0; kk < 2; ++kk) {
      const int krd = kk * 32 + krd0;
      bf16x8 af[4], bfr[4];
#pragma unroll
      for (int m = 0; m < 4; ++m)
        af[m] = __builtin_bit_cast(bf16x8,
            *reinterpret_cast<const u16x8*>(&Asm_[cur][(wr * 64 + m * 16 + rb) * BK + krd]));
#pragma unroll
      for (int n = 0; n < 4; ++n)
        bfr[n] = __builtin_bit_cast(bf16x8,
            *reinterpret_cast<const u16x8*>(&Bsm_[cur][(wc * 64 + n * 16 + rb) * BK + krd]));
#pragma unroll
      for (int m = 0; m < 4; ++m)
#pragma unroll
        for (int n = 0; n < 4; ++n)
          acc[m][n] = __builtin_amdgcn_mfma_f32_16x16x32_bf16(af[m], bfr[n], acc[m][n], 0, 0, 0);
    }
    if (next) writeA(cur ^ 1);             // cvt + ds_write after MFMA issue
    __syncthreads();
    cur ^= 1;
  }

  // C/D layout (verified m89): col = lane&15, row = (lane>>4)*4 + reg
  const int crow = row0 + wr * 64 + (lane >> 4) * 4;
  const int ccol = col0 + wc * 64 + (lane & 15);
#pragma unroll
  for (int n = 0; n < 4; ++n) {
    int c = ccol + n * 16;
    float bv = bias[c];
#pragma unroll
    for (int m = 0; m < 4; ++m)
#pragma unroll
      for (int v = 0; v < 4; ++v)
        out[(size_t)(crow + m * 16 + v) * NDIM + c] = acc[m][n][v] + bv;
  }
}

// ---------------------------------------------------------------------------
// Workspace-free fallback (slow but correct)
// ---------------------------------------------------------------------------
__global__ void fallback_kernel(const float* __restrict__ x, const float* __restrict__ A,
                                const float* __restrict__ fB, const float* __restrict__ bias,
                                float* __restrict__ out) {
  __shared__ float xrow[1024];
  const int n = blockIdx.x;
  const int tid = threadIdx.x;
  for (int t = tid; t < 1024; t += 256) xrow[t] = x[(size_t)n * 1024 + t];
  __syncthreads();
  for (int pp = 0; pp < 4; ++pp) {
    int p = pp * 256 + tid;
    int k = p >> 6, j = p & 63;
    int kb = k >> 2, ks = k & 3;
    float accv = 0.f;
    for (int s = 0; s < 16; ++s) {
      int sb = s >> 2, ss = s & 3;
      int comp = c_comp[kb][sb];
      float sgn = c_sign[kb][sb];
      float hA[RANKS];
#pragma unroll
      for (int r = 0; r < RANKS; ++r) hA[r] = sgn * A[r * 64 + comp * 16 + ks * 4 + ss];
      for (int i = 0; i < 64; ++i) {
        float w = 0.f;
#pragma unroll
        for (int r = 0; r < RANKS; ++r) w += hA[r] * fB[r * 4096 + j * 64 + i];
        accv += xrow[s * 64 + i] * w;
      }
    }
    out[(size_t)n * 1024 + p] = accv + bias[p];
  }
}

extern "C" void kernel_launch(void* const* d_in, const int* in_sizes, int n_in,
                              void* d_out, int out_size, void* d_ws, size_t ws_size,
                              hipStream_t stream) {
  const float* x    = (const float*)d_in[0];
  const float* A    = (const float*)d_in[1];
  const float* fB   = (const float*)d_in[2];
  const float* bias = (const float*)d_in[3];
  float* out = (float*)d_out;

  const size_t needW = (size_t)NDIM * KDIM * sizeof(unsigned short);
  if (ws_size >= needW) {
    unsigned short* W = (unsigned short*)d_ws;
    build_W<<<dim3(1024), dim3(256), 0, stream>>>(A, fB, W);
    gemm_ham<<<dim3((MDIM / BM) * (NDIM / BN)), dim3(256), 0, stream>>>(x, W, bias, out);
  } else {
    fallback_kernel<<<dim3(MDIM), dim3(256), 0, stream>>>(x, A, fB, bias, out);
  }
}

// Round 3
// 36.509 us; speedup vs baseline: 1.1909x; 1.1105x over previous
//
#include <hip/hip_runtime.h>
#include <stdint.h>

#define RANKS 8
#define MDIM 8192   // B*T*D / 1024 rows
#define KDIM 1024
#define NDIM 1024
#define BM 256
#define BN 128
#define BK 64
#define NT (KDIM / BK)   // 16
#define THREADS 512

typedef __bf16 bf16x8 __attribute__((ext_vector_type(8)));
typedef unsigned short u16x8 __attribute__((ext_vector_type(8)));
typedef float f32x4 __attribute__((ext_vector_type(4)));

__device__ __forceinline__ unsigned short f2bf(float f) {
  union { float f; uint32_t u; } v; v.f = f;
  uint32_t u = v.u;
  u += 0x7FFFu + ((u >> 16) & 1u);   // round-to-nearest-even
  return (unsigned short)(u >> 16);
}

// Hamilton block tables
__constant__ int   c_comp[4][4] = {{0,1,2,3},{1,0,3,2},{2,3,0,1},{3,2,1,0}};
__constant__ float c_sign[4][4] = {{1.f,-1.f,-1.f,-1.f},
                                   {1.f, 1.f,-1.f, 1.f},
                                   {1.f, 1.f, 1.f,-1.f},
                                   {1.f,-1.f, 1.f, 1.f}};

// ---------------------------------------------------------------------------
// W[p][q] = sum_r H[r,k,s] * fB[r,j,i],  p = k*64+j, q = s*64+i.  bf16 out.
// ---------------------------------------------------------------------------
__global__ void build_W(const float* __restrict__ A, const float* __restrict__ fB,
                        unsigned short* __restrict__ W) {
  int idx = blockIdx.x * 256 + threadIdx.x;
  int p  = idx >> 8;
  int q4 = (idx & 255) << 2;
  int k = p >> 6, j = p & 63;
  int kb = k >> 2, ks = k & 3;
  int s = q4 >> 6;
  int sb = s >> 2, ss = s & 3;
  int   comp = c_comp[kb][sb];
  float sgn  = c_sign[kb][sb];
  float o0 = 0.f, o1 = 0.f, o2 = 0.f, o3 = 0.f;
  int i0 = q4 & 63;
#pragma unroll
  for (int r = 0; r < RANKS; ++r) {
    float h = sgn * A[r * 64 + comp * 16 + ks * 4 + ss];
    const float* fb = fB + r * 4096 + j * 64 + i0;
    o0 += h * fb[0]; o1 += h * fb[1]; o2 += h * fb[2]; o3 += h * fb[3];
  }
  ushort4 st;
  st.x = f2bf(o0); st.y = f2bf(o1); st.z = f2bf(o2); st.w = f2bf(o3);
  *reinterpret_cast<ushort4*>(W + (size_t)p * KDIM + q4) = st;
}

// ---------------------------------------------------------------------------
// Fused deep-pipelined GEMM: out = bf16(x) * W^T + bias
// T2 LDS swizzle + T3/T4 counted-vmcnt ring pipeline + T5 setprio + T1 XCD.
// ---------------------------------------------------------------------------
__device__ __forceinline__ void gload16(const unsigned short* g, unsigned short* l) {
  __builtin_amdgcn_global_load_lds(
      (const __attribute__((address_space(1))) unsigned int*)(uintptr_t)g,
      (__attribute__((address_space(3))) unsigned int*)(uintptr_t)l,
      16, 0, 0);
}

#define SWZ(r, cbyte) (((r) * 128) + ((cbyte) ^ (((r) & 7) << 4)))

__global__ __launch_bounds__(THREADS, 2) void gemm_ham(
    const float* __restrict__ x, const unsigned short* __restrict__ W,
    const float* __restrict__ bias, float* __restrict__ out) {
  __shared__ unsigned short Asm_[2][BM * BK];   // 64 KB, 2-slot ring
  __shared__ unsigned short Bsm_[3][BN * BK];   // 48 KB, 3-slot ring

  const int tid  = threadIdx.x;
  const int lane = tid & 63;
  const int wid  = tid >> 6;        // 0..7
  const int wr   = wid >> 1;        // 0..3  (M)
  const int wc   = wid & 1;         // 0..1  (N)
  const int rb   = lane & 15;
  const int qtr  = lane >> 4;       // 0..3

  // T1: XCD-chunked bijective swizzle over 256 blocks (8 XCDs x 32).
  // XCD x gets bx in [4x, 4x+4) x all 8 by -> A-panel fetched once per XCD.
  const int flat = blockIdx.x;
  const int xg = flat & 7, ig = flat >> 3;
  const int bx = xg * 4 + (ig >> 3);   // 0..31
  const int by = ig & 7;               // 0..7
  const int row0 = bx * BM;
  const int col0 = by * BN;

  f32x4 acc[4][4];
  f32x4 zero = {0.f, 0.f, 0.f, 0.f};
#pragma unroll
  for (int m = 0; m < 4; ++m)
#pragma unroll
    for (int n = 0; n < 4; ++n) acc[m][n] = zero;

  float4 arE[8], arO[8];   // 2-deep A register staging banks

  auto loadA = [&](int kt, float4 (&ar)[8]) {
    const int k0 = kt * BK;
#pragma unroll
    for (int g = 0; g < 4; ++g) {
      int id = g * 512 + tid;
      int r = id >> 3, c8 = (id & 7) << 3;
      const float* src = x + (size_t)(row0 + r) * KDIM + k0 + c8;
      ar[2 * g]     = *reinterpret_cast<const float4*>(src);
      ar[2 * g + 1] = *reinterpret_cast<const float4*>(src + 4);
    }
  };
  auto writeA = [&](unsigned short* dst, const float4 (&ar)[8]) {
#pragma unroll
    for (int g = 0; g < 4; ++g) {
      int id = g * 512 + tid;
      int r = id >> 3, c8 = (id & 7) << 3;
      bf16x8 v;
      v[0] = (__bf16)ar[2*g].x;   v[1] = (__bf16)ar[2*g].y;
      v[2] = (__bf16)ar[2*g].z;   v[3] = (__bf16)ar[2*g].w;
      v[4] = (__bf16)ar[2*g+1].x; v[5] = (__bf16)ar[2*g+1].y;
      v[6] = (__bf16)ar[2*g+1].z; v[7] = (__bf16)ar[2*g+1].w;
      *reinterpret_cast<bf16x8*>(
          reinterpret_cast<char*>(dst) + SWZ(r, c8 * 2)) = v;
    }
  };
  auto stageB = [&](int kt, int slot) {
    unsigned short* dst = &Bsm_[slot][0];
#pragma unroll
    for (int g = 0; g < 2; ++g) {
      int id = g * 512 + tid;
      int r = id >> 3, ct = id & 7;
      // linear LDS dest + inverse-swizzled global source (rule 21)
      gload16(W + (size_t)(col0 + r) * KDIM + kt * BK + ((ct ^ (r & 7)) << 3),
              dst + id * 8);
    }
  };

  // ---- tile body -----------------------------------------------------------
  auto tile = [&](int t, const unsigned short* Ard, unsigned short* Awr,
                  float4 (&arLd)[8], float4 (&arWr)[8], int scur, int sstage) {
    const bool doStage = (t + 2 < NT);
    const bool doWrite = (t + 1 < NT);
    if (doStage) {
      loadA(t + 2, arLd);            // 8 vm ops
      stageB(t + 2, sstage);         // 2 vm ops
    }
    __builtin_amdgcn_sched_barrier(0);
    const unsigned short* Brd = &Bsm_[0][0] + scur * (BN * BK);
    __builtin_amdgcn_s_setprio(1);
#pragma unroll
    for (int kk = 0; kk < 2; ++kk) {
      const int cb = (qtr * 8 + kk * 32) * 2;   // frag col byte offset
      bf16x8 af[4], bfr[4];
#pragma unroll
      for (int m = 0; m < 4; ++m) {
        int r = wr * 64 + m * 16 + rb;
        af[m] = *reinterpret_cast<const bf16x8*>(
            reinterpret_cast<const char*>(Ard) + SWZ(r, cb));
      }
#pragma unroll
      for (int n = 0; n < 4; ++n) {
        int r = wc * 64 + n * 16 + rb;
        bfr[n] = *reinterpret_cast<const bf16x8*>(
            reinterpret_cast<const char*>(Brd) + SWZ(r, cb));
      }
#pragma unroll
      for (int m = 0; m < 4; ++m)
#pragma unroll
        for (int n = 0; n < 4; ++n)
          acc[m][n] = __builtin_amdgcn_mfma_f32_16x16x32_bf16(af[m], bfr[n], acc[m][n], 0, 0, 0);
    }
    __builtin_amdgcn_s_setprio(0);
    if (doWrite) writeA(Awr, arWr);  // compiler inserts counted vmcnt for arWr
    __builtin_amdgcn_sched_barrier(0);
    if (t < NT - 1) {
      if (doStage) asm volatile("s_waitcnt vmcnt(10)" ::: "memory");  // B(t+1) landed
      else         asm volatile("s_waitcnt vmcnt(0)"  ::: "memory");
      asm volatile("s_waitcnt lgkmcnt(0)" ::: "memory");              // A ds_writes visible
      __builtin_amdgcn_sched_barrier(0);
      __builtin_amdgcn_s_barrier();
      __builtin_amdgcn_sched_barrier(0);
    }
  };

  // ---- prologue: stage tiles 0 and 1 --------------------------------------
  loadA(0, arE);
  writeA(&Asm_[0][0], arE);          // compiler waits A(0) loads
  stageB(0, 0);
  loadA(1, arO);
  stageB(1, 1);
  asm volatile("s_waitcnt vmcnt(10)" ::: "memory");   // B(0) landed; A(1)+B(1)=10 in flight
  asm volatile("s_waitcnt lgkmcnt(0)" ::: "memory");
  __builtin_amdgcn_sched_barrier(0);
  __builtin_amdgcn_s_barrier();
  __builtin_amdgcn_sched_barrier(0);

  // ---- main loop: even/odd pairs keep reg banks statically indexed --------
  int sc = 0;
#pragma unroll 1
  for (int t2 = 0; t2 < NT; t2 += 2) {
    int ss0 = (sc == 0) ? 2 : sc - 1;          // (sc+2)%3
    tile(t2, &Asm_[0][0], &Asm_[1][0], arE, arO, sc, ss0);
    sc = (sc == 2) ? 0 : sc + 1;
    int ss1 = (sc == 0) ? 2 : sc - 1;
    tile(t2 + 1, &Asm_[1][0], &Asm_[0][0], arO, arE, sc, ss1);
    sc = (sc == 2) ? 0 : sc + 1;
  }

  // ---- epilogue: C/D layout col=lane&15, row=(lane>>4)*4+reg --------------
  const int crow = row0 + wr * 64 + qtr * 4;
  const int ccol = col0 + wc * 64 + rb;
#pragma unroll
  for (int n = 0; n < 4; ++n) {
    int c = ccol + n * 16;
    float bv = bias[c];
#pragma unroll
    for (int m = 0; m < 4; ++m)
#pragma unroll
      for (int v = 0; v < 4; ++v)
        out[(size_t)(crow + m * 16 + v) * NDIM + c] = acc[m][n][v] + bv;
  }
}

// ---------------------------------------------------------------------------
// Workspace-free fallback (slow but correct)
// ---------------------------------------------------------------------------
__global__ void fallback_kernel(const float* __restrict__ x, const float* __restrict__ A,
                                const float* __restrict__ fB, const float* __restrict__ bias,
                                float* __restrict__ out) {
  __shared__ float xrow[1024];
  const int n = blockIdx.x;
  const int tid = threadIdx.x;
  for (int t = tid; t < 1024; t += 256) xrow[t] = x[(size_t)n * 1024 + t];
  __syncthreads();
  for (int pp = 0; pp < 4; ++pp) {
    int p = pp * 256 + tid;
    int k = p >> 6, j = p & 63;
    int kb = k >> 2, ks = k & 3;
    float accv = 0.f;
    for (int s = 0; s < 16; ++s) {
      int sb = s >> 2, ss = s & 3;
      int comp = c_comp[kb][sb];
      float sgn = c_sign[kb][sb];
      float hA[RANKS];
#pragma unroll
      for (int r = 0; r < RANKS; ++r) hA[r] = sgn * A[r * 64 + comp * 16 + ks * 4 + ss];
      for (int i = 0; i < 64; ++i) {
        float w = 0.f;
#pragma unroll
        for (int r = 0; r < RANKS; ++r) w += hA[r] * fB[r * 4096 + j * 64 + i];
        accv += xrow[s * 64 + i] * w;
      }
    }
    out[(size_t)n * 1024 + p] = accv + bias[p];
  }
}

extern "C" void kernel_launch(void* const* d_in, const int* in_sizes, int n_in,
                              void* d_out, int out_size, void* d_ws, size_t ws_size,
                              hipStream_t stream) {
  const float* x    = (const float*)d_in[0];
  const float* A    = (const float*)d_in[1];
  const float* fB   = (const float*)d_in[2];
  const float* bias = (const float*)d_in[3];
  float* out = (float*)d_out;

  const size_t needW = (size_t)NDIM * KDIM * sizeof(unsigned short);
  if (ws_size >= needW) {
    unsigned short* W = (unsigned short*)d_ws;
    build_W<<<dim3(1024), dim3(256), 0, stream>>>(A, fB, W);
    gemm_ham<<<dim3((MDIM / BM) * (NDIM / BN)), dim3(THREADS), 0, stream>>>(x, W, bias, out);
  } else {
    fallback_kernel<<<dim3(MDIM), dim3(256), 0, stream>>>(x, A, fB, bias, out);
  }
}